// Round 3
// baseline (14423.955 us; speedup 1.0000x reference)
//
#include <hip/hip_runtime.h>
#include <stdint.h>

// ---------------------------------------------------------------------------
// ComplexApproximateBNN, round 6. R5 post-mortem: per-phase L2 invalidation
// (grid-barrier acquire fence) forced ~32 MB/phase W refetch from L3/HBM at
// ~1.2 TB/s -> 26 us/phase. Fix: hold ALL of W_h in REGISTERS (registers
// survive buffer_inv): 64 MB / 256 blocks / 512 thr = 128 VGPR/thread.
//  - block = (n-tile 16 cols, K-half 2048); 8 waves x 256-k slices.
//  - W preloaded once: wf[4 layers][8 ksteps] bf16x8, statically indexed.
//  - K-pair combine: kh=1 writes f32 partial + release fence + flag;
//    kh=0 spins, acquire fence, combines (+ l2norm scale on the kh=1 half,
//    which is exactly the A2 operand), act, ss, writes bf16 h.
//  - 1 grid barrier per phase (4/step), same proven R5 grid_sync.
// ---------------------------------------------------------------------------

typedef __bf16 bf16;
typedef __attribute__((ext_vector_type(8))) __bf16 bf16x8;
typedef __attribute__((ext_vector_type(4))) float f32x4;

#define BATCH 64
#define TSTEPS 128
#define INDIM 512
#define XDIM 2048
#define OUTDIM 256
#define SLOTE ((size_t)BATCH * XDIM)  // elements per [b][2048] slot
#define NBLOCKS 256

__device__ __forceinline__ float apply_act(float h, int id) {
  switch (id) {
    case 0: return fmaxf(h, 0.0f);                       // relu
    case 1: return 1.0f / (1.0f + __expf(-h));           // sigmoid
    case 2: return tanhf(h);                             // tanh
    case 3: return h >= 0.0f ? h : 0.1f * h;             // leaky 0.1
    default: {                                           // selu
      const float sc = 1.0507009873554805f;
      const float al = 1.6732632423543772f;
      return h > 0.0f ? sc * h : sc * al * (__expf(h) - 1.0f);
    }
  }
}

// Grid-wide barrier (R5-proven). Entry __syncthreads drains vmcnt; thread 0's
// agent-release fence (wbl2) publishes; acquire fence (inv) after the spin.
__device__ __forceinline__ void grid_sync(unsigned* bar, unsigned target) {
  __syncthreads();
  if (threadIdx.x == 0) {
    __builtin_amdgcn_fence(__ATOMIC_RELEASE, "agent");
    __hip_atomic_fetch_add(bar, 1u, __ATOMIC_RELAXED, __HIP_MEMORY_SCOPE_AGENT);
    while (__hip_atomic_load(bar, __ATOMIC_RELAXED, __HIP_MEMORY_SCOPE_AGENT) < target) {
      __builtin_amdgcn_s_sleep(1);
    }
    __builtin_amdgcn_fence(__ATOMIC_ACQUIRE, "agent");
  }
  __syncthreads();
}

// One layer phase. Block (nt, kh): partial[64,16] = A_kh[64,2048] @ Wslice^T
// with W entirely in registers (wf[8] per wave = 16 rows x 256 k).
// kh=1: publish partial + flag. kh=0: wait, combine, act, ss, write h.
template <bool SCALE_A2, bool EMIT_SS>
__device__ __forceinline__ void layer_phase(
    const int tid, const int nt, const int kh,
    const bf16* __restrict__ A1, const bf16* __restrict__ A2,
    const bf16x8 (&wf)[8], const float* __restrict__ bias,
    const int* __restrict__ acts, const float* __restrict__ ss_in,
    float* __restrict__ ss_out, bf16* __restrict__ outb,
    float* __restrict__ pbuf, unsigned* __restrict__ flags,
    const unsigned fv, float (&red)[8][64][17]) {
  const int lane = tid & 63;
  const int w = tid >> 6;        // 0..7 : 256-k slice within the 2048 K-half
  const int l15 = lane & 15;
  const int kb8 = (lane >> 4) * 8;

  const bf16* Ab = (kh ? A2 : A1) + (size_t)l15 * 2048 + w * 256 + kb8;

  f32x4 acc[4];
  const f32x4 zero = {0.f, 0.f, 0.f, 0.f};
#pragma unroll
  for (int mt = 0; mt < 4; mt++) acc[mt] = zero;

#pragma unroll
  for (int ks = 0; ks < 8; ks++) {
#pragma unroll
    for (int mt = 0; mt < 4; mt++) {
      bf16x8 a = *(const bf16x8*)(Ab + (size_t)mt * 16 * 2048 + ks * 32);
      acc[mt] = __builtin_amdgcn_mfma_f32_16x16x32_bf16(a, wf[ks], acc[mt], 0, 0, 0);
    }
  }

  const int q4 = lane >> 4;
#pragma unroll
  for (int mt = 0; mt < 4; mt++)
#pragma unroll
    for (int r = 0; r < 4; r++)
      red[w][mt * 16 + q4 * 4 + r][l15] = acc[mt][r];
  __syncthreads();

  const int row = tid >> 3;      // 0..63 (batch row)
  const int c0 = (tid & 7) * 2;  // even col within n-tile
  float v0 = 0.f, v1 = 0.f;
#pragma unroll
  for (int ww = 0; ww < 8; ww++) {
    v0 += red[ww][row][c0];
    v1 += red[ww][row][c0 + 1];
  }

  float* pp = pbuf + (size_t)nt * 1024 + row * 16 + c0;
  if (kh) {
    // producer: publish the A2-half partial
    float2 pv;
    pv.x = v0;
    pv.y = v1;
    *(float2*)pp = pv;
    __syncthreads();  // drain all threads' partial stores to L2
    if (tid == 0) {
      __builtin_amdgcn_fence(__ATOMIC_RELEASE, "agent");
      __hip_atomic_store(flags + nt * 16, fv, __ATOMIC_RELAXED,
                         __HIP_MEMORY_SCOPE_AGENT);
    }
  } else {
    // combiner
    if (tid == 0) {
      while (__hip_atomic_load(flags + nt * 16, __ATOMIC_RELAXED,
                               __HIP_MEMORY_SCOPE_AGENT) < fv) {
        __builtin_amdgcn_s_sleep(1);
      }
      __builtin_amdgcn_fence(__ATOMIC_ACQUIRE, "agent");
    }
    __syncthreads();
    float2 pv = *(const float2*)pp;
    float scale = 1.0f;
    if (SCALE_A2) scale = 1.0f / fmaxf(sqrtf(ss_in[row]), 1e-12f);
    const int c = nt * 16 + c0;
    float u0 = v0 + scale * pv.x + bias[c];
    float u1 = v1 + scale * pv.y + bias[c + 1];
    v0 = apply_act(u0, acts[c]);
    v1 = apply_act(u1, acts[c + 1]);
    if (EMIT_SS) {
      float ss = v0 * v0 + v1 * v1;
      ss += __shfl_xor(ss, 1);
      ss += __shfl_xor(ss, 2);
      ss += __shfl_xor(ss, 4);
      if ((tid & 7) == 0) atomicAdd(ss_out + row, ss);
    }
    union { bf16 b2[2]; uint32_t u; } pk;
    pk.b2[0] = (bf16)v0;
    pk.b2[1] = (bf16)v1;
    *(uint32_t*)(outb + (size_t)row * XDIM + c) = pk.u;
  }
}

struct StepParams {
  bf16* h0;           // [128][64][2048], slices also reused as h4 slots 2..
  bf16* extra;        // h4 slots 0,1
  bf16* h1;
  bf16* h2a;
  bf16* h2b;
  bf16* h3;
  const bf16* whb;    // [4][2048][4096]
  const float* b_h;   // [4][2048]
  const int* acts;    // [5][2048]
  float* ss_li;       // [(T+1)*64]
  float* ss_bp;       // [(T+1)*64]
  float* pbuf;        // [128][64][16] f32 partials
  unsigned* flags;    // [128*16] p2p flags (64B stride)
  unsigned* bar;      // grid barrier counter (zeroed)
};

__global__ __launch_bounds__(512, 2) void step_loop(StepParams p) {
  __shared__ float red[8][64][17];
  const int tid = threadIdx.x;
  const int bid = blockIdx.x;
  const int nt = bid & 127;   // n-tile (16 cols)
  const int kh = bid >> 7;    // K-half (0: A1, 1: A2)
  const int lane = tid & 63;
  const int w = tid >> 6;
  const int l15 = lane & 15;
  const int kb8 = (lane >> 4) * 8;
  const size_t wstr = (size_t)XDIM * 2 * XDIM;

  // One-time W preload into registers: 4 layers x 8 ksteps x bf16x8 = 128 VGPR.
  const bf16* wb = p.whb + (size_t)(nt * 16 + l15) * 4096 + kh * 2048 + w * 256 + kb8;
  bf16x8 wf0[8], wf1[8], wf2[8], wf3[8];
#pragma unroll
  for (int ks = 0; ks < 8; ks++) {
    wf0[ks] = *(const bf16x8*)(wb + ks * 32);
    wf1[ks] = *(const bf16x8*)(wb + wstr + ks * 32);
    wf2[ks] = *(const bf16x8*)(wb + 2 * wstr + ks * 32);
    wf3[ks] = *(const bf16x8*)(wb + 3 * wstr + ks * 32);
  }

  unsigned tgt = 0;
  for (int t = 0; t < TSTEPS; t++) {
    const bf16* h4t = (t < 2) ? p.extra + (size_t)t * SLOTE
                              : p.h0 + (size_t)(t - 2) * SLOTE;
    bf16* h4n = (t + 1 < 2) ? p.extra + (size_t)(t + 1) * SLOTE
                            : p.h0 + (size_t)(t - 1) * SLOTE;
    bf16* h2n = (t & 1) ? p.h2b : p.h2a;
    const bf16* h2o = (t & 1) ? p.h2a : p.h2b;

    // h1 = act([h0_t, norm(h4_t)] @ W0^T + b0)
    layer_phase<true, false>(tid, nt, kh, p.h0 + (size_t)t * SLOTE, h4t,
                             wf0, p.b_h, p.acts + XDIM, p.ss_bp + t * BATCH,
                             nullptr, p.h1, p.pbuf, p.flags, t * 4u + 1u, red);
    tgt += NBLOCKS; grid_sync(p.bar, tgt);

    // h2 = act([h1, norm(h2_old)] @ W1^T + b1); emit ss_li[t+1]
    layer_phase<true, true>(tid, nt, kh, p.h1, h2o, wf1, p.b_h + XDIM,
                            p.acts + 2 * XDIM, p.ss_li + t * BATCH,
                            p.ss_li + (t + 1) * BATCH, h2n, p.pbuf, p.flags,
                            t * 4u + 2u, red);
    tgt += NBLOCKS; grid_sync(p.bar, tgt);

    // h3 = act([h2, h1] @ W2^T + b2)
    layer_phase<false, false>(tid, nt, kh, h2n, p.h1, wf2, p.b_h + 2 * XDIM,
                              p.acts + 3 * XDIM, nullptr, nullptr, p.h3,
                              p.pbuf, p.flags, t * 4u + 3u, red);
    tgt += NBLOCKS; grid_sync(p.bar, tgt);

    // h4 = act([h3, h2] @ W3^T + b3) -> slot t+1; emit ss_bp[t+1]
    layer_phase<false, true>(tid, nt, kh, p.h3, h2n, wf3, p.b_h + 3 * XDIM,
                             p.acts + 4 * XDIM, nullptr,
                             p.ss_bp + (t + 1) * BATCH, h4n, p.pbuf, p.flags,
                             t * 4u + 4u, red);
    tgt += NBLOCKS; grid_sync(p.bar, tgt);
  }
}

// h0 precompute: [8192,512]@[512->2048], rows r=b*128+t remapped to [t][b][n]
__global__ __launch_bounds__(256) void h0_gemm(
    const bf16* __restrict__ A, const bf16* __restrict__ W,
    const float* __restrict__ bias, const int* __restrict__ acts,
    bf16* __restrict__ outp) {
  const int tid = threadIdx.x;
  const int lane = tid & 63;
  const int wv = tid >> 6;
  const int wm = (wv & 1) * 32;
  const int wn = (wv >> 1) * 64;
  const int nblk = blockIdx.x * 128;
  const int mblk = blockIdx.y * 64;
  const int l15 = lane & 15;
  const int kb8 = (lane >> 4) * 8;

  f32x4 acc[2][4];
  const f32x4 zero = {0.f, 0.f, 0.f, 0.f};
#pragma unroll
  for (int i = 0; i < 2; i++)
#pragma unroll
    for (int j = 0; j < 4; j++) acc[i][j] = zero;

  for (int kt = 0; kt < INDIM; kt += 32) {
    bf16x8 a[2], b[4];
#pragma unroll
    for (int mt = 0; mt < 2; mt++) {
      int m = mblk + wm + mt * 16 + l15;
      a[mt] = *(const bf16x8*)(A + (size_t)m * INDIM + kt + kb8);
    }
#pragma unroll
    for (int nt = 0; nt < 4; nt++) {
      int n = nblk + wn + nt * 16 + l15;
      b[nt] = *(const bf16x8*)(W + (size_t)n * INDIM + kt + kb8);
    }
#pragma unroll
    for (int mt = 0; mt < 2; mt++)
#pragma unroll
      for (int nt = 0; nt < 4; nt++)
        acc[mt][nt] = __builtin_amdgcn_mfma_f32_16x16x32_bf16(a[mt], b[nt], acc[mt][nt], 0, 0, 0);
  }

#pragma unroll
  for (int mt = 0; mt < 2; mt++) {
#pragma unroll
    for (int nt = 0; nt < 4; nt++) {
      int n = nblk + wn + nt * 16 + l15;
      float bv = bias[n];
      int aid = acts[n];
#pragma unroll
      for (int rr = 0; rr < 4; rr++) {
        int m = wm + mt * 16 + (lane >> 4) * 4 + rr;
        float v = apply_act(acc[mt][nt][rr] + bv, aid);
        int rowg = mblk + m;  // = b*128 + t
        int bb = rowg >> 7;
        int tt = rowg & 127;
        outp[((size_t)tt * BATCH + bb) * XDIM + n] = (bf16)v;
      }
    }
  }
}

// batched output layer: for each t, y_t = act(h4slot(t+1) @ Wout^T + bout).
__global__ __launch_bounds__(256) void ybat_gemm(
    const bf16* __restrict__ extra, const bf16* __restrict__ h0,
    const bf16* __restrict__ Wout, const float* __restrict__ bout,
    const int* __restrict__ oact, float* __restrict__ out) {
  const int t = blockIdx.y;
  const int s = t + 1;
  const bf16* A = (s < 2) ? (extra + (size_t)s * SLOTE)
                          : (h0 + (size_t)(s - 2) * SLOTE);
  const int tid = threadIdx.x;
  const int lane = tid & 63;
  const int wv = tid >> 6;
  const int wm = (wv & 1) * 32;
  const int wn = (wv >> 1) * 64;
  const int nblk = blockIdx.x * 128;
  const int l15 = lane & 15;
  const int kb8 = (lane >> 4) * 8;

  f32x4 acc[2][4];
  const f32x4 zero = {0.f, 0.f, 0.f, 0.f};
#pragma unroll
  for (int i = 0; i < 2; i++)
#pragma unroll
    for (int j = 0; j < 4; j++) acc[i][j] = zero;

  for (int kt = 0; kt < XDIM; kt += 32) {
    bf16x8 a[2], b[4];
#pragma unroll
    for (int mt = 0; mt < 2; mt++) {
      int m = wm + mt * 16 + l15;
      a[mt] = *(const bf16x8*)(A + (size_t)m * XDIM + kt + kb8);
    }
#pragma unroll
    for (int nt = 0; nt < 4; nt++) {
      int n = nblk + wn + nt * 16 + l15;
      b[nt] = *(const bf16x8*)(Wout + (size_t)n * XDIM + kt + kb8);
    }
#pragma unroll
    for (int mt = 0; mt < 2; mt++)
#pragma unroll
      for (int nt = 0; nt < 4; nt++)
        acc[mt][nt] = __builtin_amdgcn_mfma_f32_16x16x32_bf16(a[mt], b[nt], acc[mt][nt], 0, 0, 0);
  }

#pragma unroll
  for (int mt = 0; mt < 2; mt++) {
#pragma unroll
    for (int nt = 0; nt < 4; nt++) {
      int n = nblk + wn + nt * 16 + l15;
      float bv = bout[n];
      int aid = oact[n];
#pragma unroll
      for (int rr = 0; rr < 4; rr++) {
        int b = wm + mt * 16 + (lane >> 4) * 4 + rr;  // batch row
        float v = apply_act(acc[mt][nt][rr] + bv, aid);
        out[((size_t)b * TSTEPS + t) * OUTDIM + n] = v;
      }
    }
  }
}

__global__ __launch_bounds__(256) void cvt_bf16(
    const float* __restrict__ in, bf16* __restrict__ out, int n4) {
  int i = blockIdx.x * 256 + threadIdx.x;
  if (i < n4) {
    float4 v = ((const float4*)in)[i];
    union { bf16 b[4]; unsigned long long u; } pk;
    pk.b[0] = (bf16)v.x;
    pk.b[1] = (bf16)v.y;
    pk.b[2] = (bf16)v.z;
    pk.b[3] = (bf16)v.w;
    ((unsigned long long*)out)[i] = pk.u;
  }
}

__global__ __launch_bounds__(256) void zero32(uint32_t* __restrict__ p, int n) {
  int i = blockIdx.x * 256 + threadIdx.x;
  if (i < n) p[i] = 0u;
}

extern "C" void kernel_launch(void* const* d_in, const int* in_sizes, int n_in,
                              void* d_out, int out_size, void* d_ws, size_t ws_size,
                              hipStream_t stream) {
  const float* x     = (const float*)d_in[0];   // [64,128,512]
  const float* W_in  = (const float*)d_in[1];   // [2048,512]
  const float* b_in  = (const float*)d_in[2];   // [2048]
  const float* W_h   = (const float*)d_in[3];   // [4,2048,4096]
  const float* b_h   = (const float*)d_in[4];   // [4,2048]
  const float* W_out = (const float*)d_in[5];   // [256,2048]
  const float* b_out = (const float*)d_in[6];   // [256]
  const int* act_ids = (const int*)d_in[7];     // [5,2048]
  const int* out_act = (const int*)d_in[8];     // [256]
  float* out = (float*)d_out;                   // [64,128,256]

  char* w = (char*)d_ws;
  bf16* xbf   = (bf16*)w; w += (size_t)BATCH * TSTEPS * INDIM * 2;   // 8 MB
  bf16* winb  = (bf16*)w; w += (size_t)XDIM * INDIM * 2;             // 2 MB
  bf16* whb   = (bf16*)w; w += (size_t)4 * XDIM * (2 * XDIM) * 2;    // 64 MB
  bf16* woutb = (bf16*)w; w += (size_t)OUTDIM * XDIM * 2;            // 1 MB
  bf16* h0    = (bf16*)w; w += (size_t)TSTEPS * SLOTE * 2;           // 32 MB (doubles as h4 slots 2..)
  bf16* h1    = (bf16*)w; w += SLOTE * 2;
  bf16* h3    = (bf16*)w; w += SLOTE * 2;
  float* pbuf = (float*)w; w += (size_t)128 * 64 * 16 * 4;           // 512 KB partials
  // ---- zero region ----
  char* zstart = w;
  bf16* extra = (bf16*)w; w += 2 * SLOTE * 2;   // h4 slots 0,1 (slot 0 must be 0)
  bf16* h2a   = (bf16*)w; w += SLOTE * 2;
  bf16* h2b   = (bf16*)w; w += SLOTE * 2;
  float* ss_li = (float*)w; w += (size_t)(TSTEPS + 1) * BATCH * 4;
  float* ss_bp = (float*)w; w += (size_t)(TSTEPS + 1) * BATCH * 4;
  unsigned* flags = (unsigned*)w; w += 128 * 16 * 4;  // 8 KB, 64B stride
  unsigned* bar = (unsigned*)w; w += 256;       // barrier counter (padded)
  int zero_u32 = (int)((w - zstart) / 4);

  cvt_bf16<<<4096, 256, 0, stream>>>(x, xbf, (BATCH * TSTEPS * INDIM) / 4);
  cvt_bf16<<<1024, 256, 0, stream>>>(W_in, winb, (XDIM * INDIM) / 4);
  cvt_bf16<<<32768, 256, 0, stream>>>(W_h, whb, (4 * XDIM * 2 * XDIM) / 4);
  cvt_bf16<<<512, 256, 0, stream>>>(W_out, woutb, (OUTDIM * XDIM) / 4);
  zero32<<<(zero_u32 + 255) / 256, 256, 0, stream>>>((uint32_t*)zstart, zero_u32);
  h0_gemm<<<dim3(16, 128), 256, 0, stream>>>(xbf, winb, b_in, act_ids, h0);

  StepParams sp;
  sp.h0 = h0;
  sp.extra = extra;
  sp.h1 = h1;
  sp.h2a = h2a;
  sp.h2b = h2b;
  sp.h3 = h3;
  sp.whb = whb;
  sp.b_h = b_h;
  sp.acts = act_ids;
  sp.ss_li = ss_li;
  sp.ss_bp = ss_bp;
  sp.pbuf = pbuf;
  sp.flags = flags;
  sp.bar = bar;
  void* kp[] = {&sp};
  (void)hipLaunchCooperativeKernel((const void*)step_loop, dim3(NBLOCKS),
                                   dim3(512), kp, 0, stream);

  // all y_t in one GEMM over the stored h4 slots
  ybat_gemm<<<dim3(2, TSTEPS), 256, 0, stream>>>(
      extra, h0, woutb, b_out, out_act, out);
}

// Round 6
// 12121.468 us; speedup vs baseline: 1.1900x; 1.1900x over previous
//
#include <hip/hip_runtime.h>
#include <stdint.h>

// ---------------------------------------------------------------------------
// ComplexApproximateBNN, round 9. R7/R8 post-mortem: relaxed agent atomic
// STOREs do not write through to the coherence point (both failed ~5e7);
// RMW-write -> atomic-load-read IS proven coherent (R5's barrier counter).
// R9 = R8 with every cross-phase h-write switched to __hip_atomic_exchange
// (RMW, executes at MALL), old value kept live via empty asm so InstCombine
// cannot degrade the unused-result xchg back into an atomic store.
//  - No fences in the loop; L2 never invalidated -> W stays warm.
//  - Barrier: __syncthreads (vmcnt drain) + relaxed agent counter (proven).
//  - Cross-phase loads: 8B relaxed agent atomic loads (proven side).
// ---------------------------------------------------------------------------

typedef __bf16 bf16;
typedef __attribute__((ext_vector_type(8))) __bf16 bf16x8;
typedef __attribute__((ext_vector_type(4))) float f32x4;

#define BATCH 64
#define TSTEPS 128
#define INDIM 512
#define XDIM 2048
#define OUTDIM 256
#define SLOTE ((size_t)BATCH * XDIM)  // elements per [b][2048] slot
#define NBLOCKS 256

__device__ __forceinline__ float apply_act(float h, int id) {
  switch (id) {
    case 0: return fmaxf(h, 0.0f);                       // relu
    case 1: return 1.0f / (1.0f + __expf(-h));           // sigmoid
    case 2: return tanhf(h);                             // tanh
    case 3: return h >= 0.0f ? h : 0.1f * h;             // leaky 0.1
    default: {                                           // selu
      const float sc = 1.0507009873554805f;
      const float al = 1.6732632423543772f;
      return h > 0.0f ? sc * h : sc * al * (__expf(h) - 1.0f);
    }
  }
}

// Agent-coherent 16B load as 2x8B relaxed atomic loads (reach the coherence
// point; proven by R5's spin observing remote RMWs).
__device__ __forceinline__ bf16x8 cload(const bf16* p) {
  union { unsigned long long q[2]; bf16x8 v; } u;
  const unsigned long long* qp = (const unsigned long long*)p;
  u.q[0] = __hip_atomic_load(qp, __ATOMIC_RELAXED, __HIP_MEMORY_SCOPE_AGENT);
  u.q[1] = __hip_atomic_load(qp + 1, __ATOMIC_RELAXED, __HIP_MEMORY_SCOPE_AGENT);
  return u.v;
}

// Coherent 4B store via atomic exchange (RMW executes at coherence point).
// Old value consumed by empty asm so the xchg cannot be demoted to a store.
__device__ __forceinline__ void cstore4(uint32_t* p, uint32_t v) {
  uint32_t old = __hip_atomic_exchange(p, v, __ATOMIC_RELAXED,
                                       __HIP_MEMORY_SCOPE_AGENT);
  asm volatile("" :: "v"(old));
}

// Fence-free grid barrier: entry __syncthreads drains each thread's vmcnt
// (RMW h-stores completed at MALL before arrival); arrival + spin are
// relaxed agent atomics; no wbl2/inv anywhere.
__device__ __forceinline__ void grid_sync(unsigned* bar, unsigned target) {
  __syncthreads();
  if (threadIdx.x == 0) {
    __hip_atomic_fetch_add(bar, 1u, __ATOMIC_RELAXED, __HIP_MEMORY_SCOPE_AGENT);
    while (__hip_atomic_load(bar, __ATOMIC_RELAXED, __HIP_MEMORY_SCOPE_AGENT) < target) {
      __builtin_amdgcn_s_sleep(2);
    }
  }
  __syncthreads();
}

// One layer: C[16,32] tile of act(concat(A1,A2)[64,4096] @ W[2048,4096]^T + b)
// Block (q = m-quarter of 16 rows, nt = n-tile of 32 cols). 8 waves:
// w<4 -> A1, w>=4 -> A2, k=512 each; LDS reduce over waves.
// A reads: 8B atomic loads; W/bias/acts plain cached; C: 4B atomicExch.
template <bool SCALE_A2, bool EMIT_SS>
__device__ __forceinline__ void layer_gemm(
    const int tid, const int nt, const int q,
    const bf16* __restrict__ A1, const bf16* __restrict__ A2,
    const bf16* __restrict__ W, const float* __restrict__ bias,
    const int* __restrict__ acts, const float* __restrict__ ss_in,
    float* __restrict__ ss_out, bf16* __restrict__ outb,
    float (&red)[8][16][33]) {
  const int lane = tid & 63;
  const int w = tid >> 6;        // 0..7
  const int l15 = lane & 15;
  const int kb8 = (lane >> 4) * 8;

  const bf16* As = (w >= 4) ? A2 : A1;
  const int koff = (w & 3) * 512;   // offset within source half
  const int wk = w * 512;           // global k for W

  const bf16* ap  = As + (size_t)(q * 16 + l15) * 2048 + koff + kb8;
  const bf16* bp0 = W + (size_t)(nt * 32 + l15) * 4096 + wk + kb8;
  const bf16* bp1 = bp0 + (size_t)16 * 4096;

  f32x4 acc0 = {0.f, 0.f, 0.f, 0.f};
  f32x4 acc1 = {0.f, 0.f, 0.f, 0.f};
#pragma unroll
  for (int k = 0; k < 512; k += 32) {
    bf16x8 a  = cload(ap + k);
    bf16x8 b0 = *(const bf16x8*)(bp0 + k);
    bf16x8 b1 = *(const bf16x8*)(bp1 + k);
    acc0 = __builtin_amdgcn_mfma_f32_16x16x32_bf16(a, b0, acc0, 0, 0, 0);
    acc1 = __builtin_amdgcn_mfma_f32_16x16x32_bf16(a, b1, acc1, 0, 0, 0);
  }

  const int q4 = lane >> 4;
#pragma unroll
  for (int r = 0; r < 4; r++) {
    red[w][q4 * 4 + r][l15] = acc0[r];
    red[w][q4 * 4 + r][16 + l15] = acc1[r];
  }
  __syncthreads();

  if (tid < 256) {
    const int row = tid >> 4;        // 0..15
    const int c0 = (tid & 15) * 2;   // even col 0..30
    const int rg = q * 16 + row;     // batch row
    const int cg = nt * 32 + c0;     // output col (even)

    float lo0 = 0.f, hi0 = 0.f, lo1 = 0.f, hi1 = 0.f;
#pragma unroll
    for (int ww = 0; ww < 4; ww++) {
      lo0 += red[ww][row][c0];
      hi0 += red[ww + 4][row][c0];
      lo1 += red[ww][row][c0 + 1];
      hi1 += red[ww + 4][row][c0 + 1];
    }

    float scale = 1.0f;
    if (SCALE_A2) {
      float ssv = __hip_atomic_load(ss_in + rg, __ATOMIC_RELAXED,
                                    __HIP_MEMORY_SCOPE_AGENT);
      scale = 1.0f / fmaxf(sqrtf(ssv), 1e-12f);
    }
    float pre0 = (SCALE_A2 ? (lo0 + scale * hi0) : (lo0 + hi0)) + bias[cg];
    float pre1 = (SCALE_A2 ? (lo1 + scale * hi1) : (lo1 + hi1)) + bias[cg + 1];
    float v0 = apply_act(pre0, acts[cg]);
    float v1 = apply_act(pre1, acts[cg + 1]);

    if (EMIT_SS) {
      float ss = v0 * v0 + v1 * v1;
      ss += __shfl_xor(ss, 1);
      ss += __shfl_xor(ss, 2);
      ss += __shfl_xor(ss, 4);
      ss += __shfl_xor(ss, 8);
      if ((tid & 15) == 0) atomicAdd(ss_out + rg, ss);
    }

    union { bf16 b2[2]; uint32_t u; } pk;
    pk.b2[0] = (bf16)v0;
    pk.b2[1] = (bf16)v1;
    cstore4((uint32_t*)(outb + (size_t)rg * XDIM + cg), pk.u);
  }
}

struct StepParams {
  bf16* h0;           // [128][64][2048], slices also reused as h4 slots 2..
  bf16* extra;        // h4 slots 0,1
  bf16* h1;
  bf16* h2a;
  bf16* h2b;
  bf16* h3;
  const bf16* whb;    // [4][2048][4096]
  const float* b_h;   // [4][2048]
  const int* acts;    // [5][2048]
  float* ss_li;       // [(T+1)*64]
  float* ss_bp;       // [(T+1)*64]
  unsigned* bar;      // grid barrier counter (zeroed)
};

__global__ __launch_bounds__(512, 2) void step_loop(StepParams p) {
  __shared__ float red[8][16][33];
  const int tid = threadIdx.x;
  const int bid = blockIdx.x;
  const int nt = bid & 63;    // n-tile (32 cols)
  const int q  = bid >> 6;    // m-quarter (16 rows)
  const size_t wstr = (size_t)XDIM * 2 * XDIM;
  unsigned tgt = 0;

  for (int t = 0; t < TSTEPS; t++) {
    const bf16* h4t = (t < 2) ? p.extra + (size_t)t * SLOTE
                              : p.h0 + (size_t)(t - 2) * SLOTE;
    bf16* h4n = (t + 1 < 2) ? p.extra + (size_t)(t + 1) * SLOTE
                            : p.h0 + (size_t)(t - 1) * SLOTE;
    bf16* h2n = (t & 1) ? p.h2b : p.h2a;
    const bf16* h2o = (t & 1) ? p.h2a : p.h2b;

    // h1 = act([h0_t, norm(h4_t)] @ W0^T + b0)
    layer_gemm<true, false>(tid, nt, q, p.h0 + (size_t)t * SLOTE, h4t,
                            p.whb, p.b_h, p.acts + XDIM, p.ss_bp + t * BATCH,
                            nullptr, p.h1, red);
    tgt += NBLOCKS; grid_sync(p.bar, tgt);

    // h2 = act([h1, norm(h2_old)] @ W1^T + b1); emit ss_li[t+1]
    layer_gemm<true, true>(tid, nt, q, p.h1, h2o, p.whb + wstr,
                           p.b_h + XDIM, p.acts + 2 * XDIM,
                           p.ss_li + t * BATCH, p.ss_li + (t + 1) * BATCH,
                           h2n, red);
    tgt += NBLOCKS; grid_sync(p.bar, tgt);

    // h3 = act([h2, h1] @ W2^T + b2)
    layer_gemm<false, false>(tid, nt, q, h2n, p.h1, p.whb + 2 * wstr,
                             p.b_h + 2 * XDIM, p.acts + 3 * XDIM, nullptr,
                             nullptr, p.h3, red);
    tgt += NBLOCKS; grid_sync(p.bar, tgt);

    // h4 = act([h3, h2] @ W3^T + b3) -> slot t+1; emit ss_bp[t+1]
    layer_gemm<false, true>(tid, nt, q, p.h3, h2n, p.whb + 3 * wstr,
                            p.b_h + 3 * XDIM, p.acts + 4 * XDIM, nullptr,
                            p.ss_bp + (t + 1) * BATCH, h4n, red);
    tgt += NBLOCKS; grid_sync(p.bar, tgt);
  }
}

// h0 precompute: [8192,512]@[512->2048], rows r=b*128+t remapped to [t][b][n]
__global__ __launch_bounds__(256) void h0_gemm(
    const bf16* __restrict__ A, const bf16* __restrict__ W,
    const float* __restrict__ bias, const int* __restrict__ acts,
    bf16* __restrict__ outp) {
  const int tid = threadIdx.x;
  const int lane = tid & 63;
  const int wv = tid >> 6;
  const int wm = (wv & 1) * 32;
  const int wn = (wv >> 1) * 64;
  const int nblk = blockIdx.x * 128;
  const int mblk = blockIdx.y * 64;
  const int l15 = lane & 15;
  const int kb8 = (lane >> 4) * 8;

  f32x4 acc[2][4];
  const f32x4 zero = {0.f, 0.f, 0.f, 0.f};
#pragma unroll
  for (int i = 0; i < 2; i++)
#pragma unroll
    for (int j = 0; j < 4; j++) acc[i][j] = zero;

  for (int kt = 0; kt < INDIM; kt += 32) {
    bf16x8 a[2], b[4];
#pragma unroll
    for (int mt = 0; mt < 2; mt++) {
      int m = mblk + wm + mt * 16 + l15;
      a[mt] = *(const bf16x8*)(A + (size_t)m * INDIM + kt + kb8);
    }
#pragma unroll
    for (int nt = 0; nt < 4; nt++) {
      int n = nblk + wn + nt * 16 + l15;
      b[nt] = *(const bf16x8*)(W + (size_t)n * INDIM + kt + kb8);
    }
#pragma unroll
    for (int mt = 0; mt < 2; mt++)
#pragma unroll
      for (int nt = 0; nt < 4; nt++)
        acc[mt][nt] = __builtin_amdgcn_mfma_f32_16x16x32_bf16(a[mt], b[nt], acc[mt][nt], 0, 0, 0);
  }

#pragma unroll
  for (int mt = 0; mt < 2; mt++) {
#pragma unroll
    for (int nt = 0; nt < 4; nt++) {
      int n = nblk + wn + nt * 16 + l15;
      float bv = bias[n];
      int aid = acts[n];
#pragma unroll
      for (int rr = 0; rr < 4; rr++) {
        int m = wm + mt * 16 + (lane >> 4) * 4 + rr;
        float v = apply_act(acc[mt][nt][rr] + bv, aid);
        int rowg = mblk + m;  // = b*128 + t
        int bb = rowg >> 7;
        int tt = rowg & 127;
        outp[((size_t)tt * BATCH + bb) * XDIM + n] = (bf16)v;
      }
    }
  }
}

// batched output layer: for each t, y_t = act(h4slot(t+1) @ Wout^T + bout).
__global__ __launch_bounds__(256) void ybat_gemm(
    const bf16* __restrict__ extra, const bf16* __restrict__ h0,
    const bf16* __restrict__ Wout, const float* __restrict__ bout,
    const int* __restrict__ oact, float* __restrict__ out) {
  const int t = blockIdx.y;
  const int s = t + 1;
  const bf16* A = (s < 2) ? (extra + (size_t)s * SLOTE)
                          : (h0 + (size_t)(s - 2) * SLOTE);
  const int tid = threadIdx.x;
  const int lane = tid & 63;
  const int wv = tid >> 6;
  const int wm = (wv & 1) * 32;
  const int wn = (wv >> 1) * 64;
  const int nblk = blockIdx.x * 128;
  const int l15 = lane & 15;
  const int kb8 = (lane >> 4) * 8;

  f32x4 acc[2][4];
  const f32x4 zero = {0.f, 0.f, 0.f, 0.f};
#pragma unroll
  for (int i = 0; i < 2; i++)
#pragma unroll
    for (int j = 0; j < 4; j++) acc[i][j] = zero;

  for (int kt = 0; kt < XDIM; kt += 32) {
    bf16x8 a[2], b[4];
#pragma unroll
    for (int mt = 0; mt < 2; mt++) {
      int m = wm + mt * 16 + l15;
      a[mt] = *(const bf16x8*)(A + (size_t)m * XDIM + kt + kb8);
    }
#pragma unroll
    for (int nt = 0; nt < 4; nt++) {
      int n = nblk + wn + nt * 16 + l15;
      b[nt] = *(const bf16x8*)(Wout + (size_t)n * XDIM + kt + kb8);
    }
#pragma unroll
    for (int mt = 0; mt < 2; mt++)
#pragma unroll
      for (int nt = 0; nt < 4; nt++)
        acc[mt][nt] = __builtin_amdgcn_mfma_f32_16x16x32_bf16(a[mt], b[nt], acc[mt][nt], 0, 0, 0);
  }

#pragma unroll
  for (int mt = 0; mt < 2; mt++) {
#pragma unroll
    for (int nt = 0; nt < 4; nt++) {
      int n = nblk + wn + nt * 16 + l15;
      float bv = bout[n];
      int aid = oact[n];
#pragma unroll
      for (int rr = 0; rr < 4; rr++) {
        int b = wm + mt * 16 + (lane >> 4) * 4 + rr;  // batch row
        float v = apply_act(acc[mt][nt][rr] + bv, aid);
        out[((size_t)b * TSTEPS + t) * OUTDIM + n] = v;
      }
    }
  }
}

__global__ __launch_bounds__(256) void cvt_bf16(
    const float* __restrict__ in, bf16* __restrict__ out, int n4) {
  int i = blockIdx.x * 256 + threadIdx.x;
  if (i < n4) {
    float4 v = ((const float4*)in)[i];
    union { bf16 b[4]; unsigned long long u; } pk;
    pk.b[0] = (bf16)v.x;
    pk.b[1] = (bf16)v.y;
    pk.b[2] = (bf16)v.z;
    pk.b[3] = (bf16)v.w;
    ((unsigned long long*)out)[i] = pk.u;
  }
}

__global__ __launch_bounds__(256) void zero32(uint32_t* __restrict__ p, int n) {
  int i = blockIdx.x * 256 + threadIdx.x;
  if (i < n) p[i] = 0u;
}

extern "C" void kernel_launch(void* const* d_in, const int* in_sizes, int n_in,
                              void* d_out, int out_size, void* d_ws, size_t ws_size,
                              hipStream_t stream) {
  const float* x     = (const float*)d_in[0];   // [64,128,512]
  const float* W_in  = (const float*)d_in[1];   // [2048,512]
  const float* b_in  = (const float*)d_in[2];   // [2048]
  const float* W_h   = (const float*)d_in[3];   // [4,2048,4096]
  const float* b_h   = (const float*)d_in[4];   // [4,2048]
  const float* W_out = (const float*)d_in[5];   // [256,2048]
  const float* b_out = (const float*)d_in[6];   // [256]
  const int* act_ids = (const int*)d_in[7];     // [5,2048]
  const int* out_act = (const int*)d_in[8];     // [256]
  float* out = (float*)d_out;                   // [64,128,256]

  char* w = (char*)d_ws;
  bf16* xbf   = (bf16*)w; w += (size_t)BATCH * TSTEPS * INDIM * 2;   // 8 MB
  bf16* winb  = (bf16*)w; w += (size_t)XDIM * INDIM * 2;             // 2 MB
  bf16* whb   = (bf16*)w; w += (size_t)4 * XDIM * (2 * XDIM) * 2;    // 64 MB
  bf16* woutb = (bf16*)w; w += (size_t)OUTDIM * XDIM * 2;            // 1 MB
  bf16* h0    = (bf16*)w; w += (size_t)TSTEPS * SLOTE * 2;           // 32 MB (doubles as h4 slots 2..)
  bf16* h1    = (bf16*)w; w += SLOTE * 2;
  bf16* h3    = (bf16*)w; w += SLOTE * 2;
  // ---- zero region ----
  char* zstart = w;
  bf16* extra = (bf16*)w; w += 2 * SLOTE * 2;   // h4 slots 0,1 (slot 0 must be 0)
  bf16* h2a   = (bf16*)w; w += SLOTE * 2;
  bf16* h2b   = (bf16*)w; w += SLOTE * 2;
  float* ss_li = (float*)w; w += (size_t)(TSTEPS + 1) * BATCH * 4;
  float* ss_bp = (float*)w; w += (size_t)(TSTEPS + 1) * BATCH * 4;
  unsigned* bar = (unsigned*)w; w += 256;       // barrier counter (padded)
  int zero_u32 = (int)((w - zstart) / 4);

  cvt_bf16<<<4096, 256, 0, stream>>>(x, xbf, (BATCH * TSTEPS * INDIM) / 4);
  cvt_bf16<<<1024, 256, 0, stream>>>(W_in, winb, (XDIM * INDIM) / 4);
  cvt_bf16<<<32768, 256, 0, stream>>>(W_h, whb, (4 * XDIM * 2 * XDIM) / 4);
  cvt_bf16<<<512, 256, 0, stream>>>(W_out, woutb, (OUTDIM * XDIM) / 4);
  zero32<<<(zero_u32 + 255) / 256, 256, 0, stream>>>((uint32_t*)zstart, zero_u32);
  h0_gemm<<<dim3(16, 128), 256, 0, stream>>>(xbf, winb, b_in, act_ids, h0);

  StepParams sp;
  sp.h0 = h0;
  sp.extra = extra;
  sp.h1 = h1;
  sp.h2a = h2a;
  sp.h2b = h2b;
  sp.h3 = h3;
  sp.whb = whb;
  sp.b_h = b_h;
  sp.acts = act_ids;
  sp.ss_li = ss_li;
  sp.ss_bp = ss_bp;
  sp.bar = bar;
  void* kp[] = {&sp};
  (void)hipLaunchCooperativeKernel((const void*)step_loop, dim3(NBLOCKS),
                                   dim3(512), kp, 0, stream);

  // all y_t in one GEMM over the stored h4 slots
  ybat_gemm<<<dim3(2, TSTEPS), 256, 0, stream>>>(
      extra, h0, woutb, b_out, out_act, out);
}

// Round 7
// 10761.486 us; speedup vs baseline: 1.3403x; 1.1264x over previous
//
#include <hip/hip_runtime.h>
#include <stdint.h>

// ---------------------------------------------------------------------------
// ComplexApproximateBNN, round 10. R5/R6/R9 post-mortem: phase time ~23-27 us
// is invariant to GEMM memory traffic and fence regime -> shared cost is the
// FLAT grid barrier: 256 thread0s polling ONE MALL line every 128 cycles
// (2 loads/cy at a bank serving ~1/2-4cy) = permanent oversubscription that
// inflates every barrier op and shares queues with the phase's A-loads.
// R10 = R9 (passing, fence-free, RMW-write/atomic-load-read) with a
// TWO-LEVEL, PADDED, SLOW-POLL barrier:
//  - 8 groups x 32 blocks (bid>>5); per-group arrival counters on 256B-
//    stride lines (32-way RMW contention, fine).
//  - group-last promotes to gbar (8-way); only group-lasts poll gbar;
//    members poll their group's rel line (31 pollers/line, 8 lines).
//  - s_sleep(4) = 256cy poll interval -> <=0.12 loads/cy/line.
// Everything else byte-identical to R9.
// ---------------------------------------------------------------------------

typedef __bf16 bf16;
typedef __attribute__((ext_vector_type(8))) __bf16 bf16x8;
typedef __attribute__((ext_vector_type(4))) float f32x4;

#define BATCH 64
#define TSTEPS 128
#define INDIM 512
#define XDIM 2048
#define OUTDIM 256
#define SLOTE ((size_t)BATCH * XDIM)  // elements per [b][2048] slot
#define NBLOCKS 256
#define GSTRIDE 64                    // u32 stride between counters = 256 B

__device__ __forceinline__ float apply_act(float h, int id) {
  switch (id) {
    case 0: return fmaxf(h, 0.0f);                       // relu
    case 1: return 1.0f / (1.0f + __expf(-h));           // sigmoid
    case 2: return tanhf(h);                             // tanh
    case 3: return h >= 0.0f ? h : 0.1f * h;             // leaky 0.1
    default: {                                           // selu
      const float sc = 1.0507009873554805f;
      const float al = 1.6732632423543772f;
      return h > 0.0f ? sc * h : sc * al * (__expf(h) - 1.0f);
    }
  }
}

// Agent-coherent 16B load as 2x8B relaxed atomic loads (reach the coherence
// point; proven by R5/R9).
__device__ __forceinline__ bf16x8 cload(const bf16* p) {
  union { unsigned long long q[2]; bf16x8 v; } u;
  const unsigned long long* qp = (const unsigned long long*)p;
  u.q[0] = __hip_atomic_load(qp, __ATOMIC_RELAXED, __HIP_MEMORY_SCOPE_AGENT);
  u.q[1] = __hip_atomic_load(qp + 1, __ATOMIC_RELAXED, __HIP_MEMORY_SCOPE_AGENT);
  return u.v;
}

// Coherent 4B store via atomic exchange (RMW executes at coherence point;
// proven R9). Old value consumed by empty asm so the xchg can't demote.
__device__ __forceinline__ void cstore4(uint32_t* p, uint32_t v) {
  uint32_t old = __hip_atomic_exchange(p, v, __ATOMIC_RELAXED,
                                       __HIP_MEMORY_SCOPE_AGENT);
  asm volatile("" :: "v"(old));
}

// Two-level fence-free grid barrier (see header). ph is 1-based monotonic.
// Layout in bars[]: garr[g] @ g*GSTRIDE, gbar @ 8*GSTRIDE,
// rel[g] @ (9+g)*GSTRIDE.
__device__ __forceinline__ void grid_sync2(unsigned* bars, int bid,
                                           unsigned ph) {
  __syncthreads();
  if (threadIdx.x == 0) {
    const int g = bid >> 5;
    unsigned* garr = bars + (size_t)g * GSTRIDE;
    unsigned* gbar = bars + (size_t)8 * GSTRIDE;
    unsigned* rel  = bars + (size_t)(9 + g) * GSTRIDE;
    unsigned old = __hip_atomic_fetch_add(garr, 1u, __ATOMIC_RELAXED,
                                          __HIP_MEMORY_SCOPE_AGENT);
    if (old == 32u * ph - 1u) {
      // last block of this group: promote to global level
      unsigned gold = __hip_atomic_fetch_add(gbar, 1u, __ATOMIC_RELAXED,
                                             __HIP_MEMORY_SCOPE_AGENT);
      if (gold != 8u * ph - 1u) {
        while (__hip_atomic_load(gbar, __ATOMIC_RELAXED,
                                 __HIP_MEMORY_SCOPE_AGENT) < 8u * ph) {
          __builtin_amdgcn_s_sleep(4);
        }
      }
      __hip_atomic_fetch_add(rel, 1u, __ATOMIC_RELAXED,
                             __HIP_MEMORY_SCOPE_AGENT);
    } else {
      while (__hip_atomic_load(rel, __ATOMIC_RELAXED,
                               __HIP_MEMORY_SCOPE_AGENT) < ph) {
        __builtin_amdgcn_s_sleep(4);
      }
    }
  }
  __syncthreads();
}

// One layer: C[16,32] tile of act(concat(A1,A2)[64,4096] @ W[2048,4096]^T + b)
// Block (q = m-quarter of 16 rows, nt = n-tile of 32 cols). 8 waves:
// w<4 -> A1, w>=4 -> A2, k=512 each; LDS reduce over waves.
// A reads: 8B atomic loads; W/bias/acts plain cached; C: 4B atomicExch.
template <bool SCALE_A2, bool EMIT_SS>
__device__ __forceinline__ void layer_gemm(
    const int tid, const int nt, const int q,
    const bf16* __restrict__ A1, const bf16* __restrict__ A2,
    const bf16* __restrict__ W, const float* __restrict__ bias,
    const int* __restrict__ acts, const float* __restrict__ ss_in,
    float* __restrict__ ss_out, bf16* __restrict__ outb,
    float (&red)[8][16][33]) {
  const int lane = tid & 63;
  const int w = tid >> 6;        // 0..7
  const int l15 = lane & 15;
  const int kb8 = (lane >> 4) * 8;

  const bf16* As = (w >= 4) ? A2 : A1;
  const int koff = (w & 3) * 512;   // offset within source half
  const int wk = w * 512;           // global k for W

  const bf16* ap  = As + (size_t)(q * 16 + l15) * 2048 + koff + kb8;
  const bf16* bp0 = W + (size_t)(nt * 32 + l15) * 4096 + wk + kb8;
  const bf16* bp1 = bp0 + (size_t)16 * 4096;

  f32x4 acc0 = {0.f, 0.f, 0.f, 0.f};
  f32x4 acc1 = {0.f, 0.f, 0.f, 0.f};
#pragma unroll
  for (int k = 0; k < 512; k += 32) {
    bf16x8 a  = cload(ap + k);
    bf16x8 b0 = *(const bf16x8*)(bp0 + k);
    bf16x8 b1 = *(const bf16x8*)(bp1 + k);
    acc0 = __builtin_amdgcn_mfma_f32_16x16x32_bf16(a, b0, acc0, 0, 0, 0);
    acc1 = __builtin_amdgcn_mfma_f32_16x16x32_bf16(a, b1, acc1, 0, 0, 0);
  }

  const int q4 = lane >> 4;
#pragma unroll
  for (int r = 0; r < 4; r++) {
    red[w][q4 * 4 + r][l15] = acc0[r];
    red[w][q4 * 4 + r][16 + l15] = acc1[r];
  }
  __syncthreads();

  if (tid < 256) {
    const int row = tid >> 4;        // 0..15
    const int c0 = (tid & 15) * 2;   // even col 0..30
    const int rg = q * 16 + row;     // batch row
    const int cg = nt * 32 + c0;     // output col (even)

    float lo0 = 0.f, hi0 = 0.f, lo1 = 0.f, hi1 = 0.f;
#pragma unroll
    for (int ww = 0; ww < 4; ww++) {
      lo0 += red[ww][row][c0];
      hi0 += red[ww + 4][row][c0];
      lo1 += red[ww][row][c0 + 1];
      hi1 += red[ww + 4][row][c0 + 1];
    }

    float scale = 1.0f;
    if (SCALE_A2) {
      float ssv = __hip_atomic_load(ss_in + rg, __ATOMIC_RELAXED,
                                    __HIP_MEMORY_SCOPE_AGENT);
      scale = 1.0f / fmaxf(sqrtf(ssv), 1e-12f);
    }
    float pre0 = (SCALE_A2 ? (lo0 + scale * hi0) : (lo0 + hi0)) + bias[cg];
    float pre1 = (SCALE_A2 ? (lo1 + scale * hi1) : (lo1 + hi1)) + bias[cg + 1];
    float v0 = apply_act(pre0, acts[cg]);
    float v1 = apply_act(pre1, acts[cg + 1]);

    if (EMIT_SS) {
      float ss = v0 * v0 + v1 * v1;
      ss += __shfl_xor(ss, 1);
      ss += __shfl_xor(ss, 2);
      ss += __shfl_xor(ss, 4);
      ss += __shfl_xor(ss, 8);
      if ((tid & 15) == 0) atomicAdd(ss_out + rg, ss);
    }

    union { bf16 b2[2]; uint32_t u; } pk;
    pk.b2[0] = (bf16)v0;
    pk.b2[1] = (bf16)v1;
    cstore4((uint32_t*)(outb + (size_t)rg * XDIM + cg), pk.u);
  }
}

struct StepParams {
  bf16* h0;           // [128][64][2048], slices also reused as h4 slots 2..
  bf16* extra;        // h4 slots 0,1
  bf16* h1;
  bf16* h2a;
  bf16* h2b;
  bf16* h3;
  const bf16* whb;    // [4][2048][4096]
  const float* b_h;   // [4][2048]
  const int* acts;    // [5][2048]
  float* ss_li;       // [(T+1)*64]
  float* ss_bp;       // [(T+1)*64]
  unsigned* bar;      // barrier counters (zeroed), 32*GSTRIDE u32s
};

__global__ __launch_bounds__(512, 2) void step_loop(StepParams p) {
  __shared__ float red[8][16][33];
  const int tid = threadIdx.x;
  const int bid = blockIdx.x;
  const int nt = bid & 63;    // n-tile (32 cols)
  const int q  = bid >> 6;    // m-quarter (16 rows)
  const size_t wstr = (size_t)XDIM * 2 * XDIM;
  unsigned ph = 0;

  for (int t = 0; t < TSTEPS; t++) {
    const bf16* h4t = (t < 2) ? p.extra + (size_t)t * SLOTE
                              : p.h0 + (size_t)(t - 2) * SLOTE;
    bf16* h4n = (t + 1 < 2) ? p.extra + (size_t)(t + 1) * SLOTE
                            : p.h0 + (size_t)(t - 1) * SLOTE;
    bf16* h2n = (t & 1) ? p.h2b : p.h2a;
    const bf16* h2o = (t & 1) ? p.h2a : p.h2b;

    // h1 = act([h0_t, norm(h4_t)] @ W0^T + b0)
    layer_gemm<true, false>(tid, nt, q, p.h0 + (size_t)t * SLOTE, h4t,
                            p.whb, p.b_h, p.acts + XDIM, p.ss_bp + t * BATCH,
                            nullptr, p.h1, red);
    ++ph; grid_sync2(p.bar, bid, ph);

    // h2 = act([h1, norm(h2_old)] @ W1^T + b1); emit ss_li[t+1]
    layer_gemm<true, true>(tid, nt, q, p.h1, h2o, p.whb + wstr,
                           p.b_h + XDIM, p.acts + 2 * XDIM,
                           p.ss_li + t * BATCH, p.ss_li + (t + 1) * BATCH,
                           h2n, red);
    ++ph; grid_sync2(p.bar, bid, ph);

    // h3 = act([h2, h1] @ W2^T + b2)
    layer_gemm<false, false>(tid, nt, q, h2n, p.h1, p.whb + 2 * wstr,
                             p.b_h + 2 * XDIM, p.acts + 3 * XDIM, nullptr,
                             nullptr, p.h3, red);
    ++ph; grid_sync2(p.bar, bid, ph);

    // h4 = act([h3, h2] @ W3^T + b3) -> slot t+1; emit ss_bp[t+1]
    layer_gemm<false, true>(tid, nt, q, p.h3, h2n, p.whb + 3 * wstr,
                            p.b_h + 3 * XDIM, p.acts + 4 * XDIM, nullptr,
                            p.ss_bp + (t + 1) * BATCH, h4n, red);
    ++ph; grid_sync2(p.bar, bid, ph);
  }
}

// h0 precompute: [8192,512]@[512->2048], rows r=b*128+t remapped to [t][b][n]
__global__ __launch_bounds__(256) void h0_gemm(
    const bf16* __restrict__ A, const bf16* __restrict__ W,
    const float* __restrict__ bias, const int* __restrict__ acts,
    bf16* __restrict__ outp) {
  const int tid = threadIdx.x;
  const int lane = tid & 63;
  const int wv = tid >> 6;
  const int wm = (wv & 1) * 32;
  const int wn = (wv >> 1) * 64;
  const int nblk = blockIdx.x * 128;
  const int mblk = blockIdx.y * 64;
  const int l15 = lane & 15;
  const int kb8 = (lane >> 4) * 8;

  f32x4 acc[2][4];
  const f32x4 zero = {0.f, 0.f, 0.f, 0.f};
#pragma unroll
  for (int i = 0; i < 2; i++)
#pragma unroll
    for (int j = 0; j < 4; j++) acc[i][j] = zero;

  for (int kt = 0; kt < INDIM; kt += 32) {
    bf16x8 a[2], b[4];
#pragma unroll
    for (int mt = 0; mt < 2; mt++) {
      int m = mblk + wm + mt * 16 + l15;
      a[mt] = *(const bf16x8*)(A + (size_t)m * INDIM + kt + kb8);
    }
#pragma unroll
    for (int nt = 0; nt < 4; nt++) {
      int n = nblk + wn + nt * 16 + l15;
      b[nt] = *(const bf16x8*)(W + (size_t)n * INDIM + kt + kb8);
    }
#pragma unroll
    for (int mt = 0; mt < 2; mt++)
#pragma unroll
      for (int nt = 0; nt < 4; nt++)
        acc[mt][nt] = __builtin_amdgcn_mfma_f32_16x16x32_bf16(a[mt], b[nt], acc[mt][nt], 0, 0, 0);
  }

#pragma unroll
  for (int mt = 0; mt < 2; mt++) {
#pragma unroll
    for (int nt = 0; nt < 4; nt++) {
      int n = nblk + wn + nt * 16 + l15;
      float bv = bias[n];
      int aid = acts[n];
#pragma unroll
      for (int rr = 0; rr < 4; rr++) {
        int m = wm + mt * 16 + (lane >> 4) * 4 + rr;
        float v = apply_act(acc[mt][nt][rr] + bv, aid);
        int rowg = mblk + m;  // = b*128 + t
        int bb = rowg >> 7;
        int tt = rowg & 127;
        outp[((size_t)tt * BATCH + bb) * XDIM + n] = (bf16)v;
      }
    }
  }
}

// batched output layer: for each t, y_t = act(h4slot(t+1) @ Wout^T + bout).
__global__ __launch_bounds__(256) void ybat_gemm(
    const bf16* __restrict__ extra, const bf16* __restrict__ h0,
    const bf16* __restrict__ Wout, const float* __restrict__ bout,
    const int* __restrict__ oact, float* __restrict__ out) {
  const int t = blockIdx.y;
  const int s = t + 1;
  const bf16* A = (s < 2) ? (extra + (size_t)s * SLOTE)
                          : (h0 + (size_t)(s - 2) * SLOTE);
  const int tid = threadIdx.x;
  const int lane = tid & 63;
  const int wv = tid >> 6;
  const int wm = (wv & 1) * 32;
  const int wn = (wv >> 1) * 64;
  const int nblk = blockIdx.x * 128;
  const int l15 = lane & 15;
  const int kb8 = (lane >> 4) * 8;

  f32x4 acc[2][4];
  const f32x4 zero = {0.f, 0.f, 0.f, 0.f};
#pragma unroll
  for (int i = 0; i < 2; i++)
#pragma unroll
    for (int j = 0; j < 4; j++) acc[i][j] = zero;

  for (int kt = 0; kt < XDIM; kt += 32) {
    bf16x8 a[2], b[4];
#pragma unroll
    for (int mt = 0; mt < 2; mt++) {
      int m = wm + mt * 16 + l15;
      a[mt] = *(const bf16x8*)(A + (size_t)m * XDIM + kt + kb8);
    }
#pragma unroll
    for (int nt = 0; nt < 4; nt++) {
      int n = nblk + wn + nt * 16 + l15;
      b[nt] = *(const bf16x8*)(Wout + (size_t)n * XDIM + kt + kb8);
    }
#pragma unroll
    for (int mt = 0; mt < 2; mt++)
#pragma unroll
      for (int nt = 0; nt < 4; nt++)
        acc[mt][nt] = __builtin_amdgcn_mfma_f32_16x16x32_bf16(a[mt], b[nt], acc[mt][nt], 0, 0, 0);
  }

#pragma unroll
  for (int mt = 0; mt < 2; mt++) {
#pragma unroll
    for (int nt = 0; nt < 4; nt++) {
      int n = nblk + wn + nt * 16 + l15;
      float bv = bout[n];
      int aid = oact[n];
#pragma unroll
      for (int rr = 0; rr < 4; rr++) {
        int b = wm + mt * 16 + (lane >> 4) * 4 + rr;  // batch row
        float v = apply_act(acc[mt][nt][rr] + bv, aid);
        out[((size_t)b * TSTEPS + t) * OUTDIM + n] = v;
      }
    }
  }
}

__global__ __launch_bounds__(256) void cvt_bf16(
    const float* __restrict__ in, bf16* __restrict__ out, int n4) {
  int i = blockIdx.x * 256 + threadIdx.x;
  if (i < n4) {
    float4 v = ((const float4*)in)[i];
    union { bf16 b[4]; unsigned long long u; } pk;
    pk.b[0] = (bf16)v.x;
    pk.b[1] = (bf16)v.y;
    pk.b[2] = (bf16)v.z;
    pk.b[3] = (bf16)v.w;
    ((unsigned long long*)out)[i] = pk.u;
  }
}

__global__ __launch_bounds__(256) void zero32(uint32_t* __restrict__ p, int n) {
  int i = blockIdx.x * 256 + threadIdx.x;
  if (i < n) p[i] = 0u;
}

extern "C" void kernel_launch(void* const* d_in, const int* in_sizes, int n_in,
                              void* d_out, int out_size, void* d_ws, size_t ws_size,
                              hipStream_t stream) {
  const float* x     = (const float*)d_in[0];   // [64,128,512]
  const float* W_in  = (const float*)d_in[1];   // [2048,512]
  const float* b_in  = (const float*)d_in[2];   // [2048]
  const float* W_h   = (const float*)d_in[3];   // [4,2048,4096]
  const float* b_h   = (const float*)d_in[4];   // [4,2048]
  const float* W_out = (const float*)d_in[5];   // [256,2048]
  const float* b_out = (const float*)d_in[6];   // [256]
  const int* act_ids = (const int*)d_in[7];     // [5,2048]
  const int* out_act = (const int*)d_in[8];     // [256]
  float* out = (float*)d_out;                   // [64,128,256]

  char* w = (char*)d_ws;
  bf16* xbf   = (bf16*)w; w += (size_t)BATCH * TSTEPS * INDIM * 2;   // 8 MB
  bf16* winb  = (bf16*)w; w += (size_t)XDIM * INDIM * 2;             // 2 MB
  bf16* whb   = (bf16*)w; w += (size_t)4 * XDIM * (2 * XDIM) * 2;    // 64 MB
  bf16* woutb = (bf16*)w; w += (size_t)OUTDIM * XDIM * 2;            // 1 MB
  bf16* h0    = (bf16*)w; w += (size_t)TSTEPS * SLOTE * 2;           // 32 MB (doubles as h4 slots 2..)
  bf16* h1    = (bf16*)w; w += SLOTE * 2;
  bf16* h3    = (bf16*)w; w += SLOTE * 2;
  // ---- zero region ----
  char* zstart = w;
  bf16* extra = (bf16*)w; w += 2 * SLOTE * 2;   // h4 slots 0,1 (slot 0 must be 0)
  bf16* h2a   = (bf16*)w; w += SLOTE * 2;
  bf16* h2b   = (bf16*)w; w += SLOTE * 2;
  float* ss_li = (float*)w; w += (size_t)(TSTEPS + 1) * BATCH * 4;
  float* ss_bp = (float*)w; w += (size_t)(TSTEPS + 1) * BATCH * 4;
  unsigned* bar = (unsigned*)w; w += (size_t)32 * GSTRIDE * 4;  // padded counters
  int zero_u32 = (int)((w - zstart) / 4);

  cvt_bf16<<<4096, 256, 0, stream>>>(x, xbf, (BATCH * TSTEPS * INDIM) / 4);
  cvt_bf16<<<1024, 256, 0, stream>>>(W_in, winb, (XDIM * INDIM) / 4);
  cvt_bf16<<<32768, 256, 0, stream>>>(W_h, whb, (4 * XDIM * 2 * XDIM) / 4);
  cvt_bf16<<<512, 256, 0, stream>>>(W_out, woutb, (OUTDIM * XDIM) / 4);
  zero32<<<(zero_u32 + 255) / 256, 256, 0, stream>>>((uint32_t*)zstart, zero_u32);
  h0_gemm<<<dim3(16, 128), 256, 0, stream>>>(xbf, winb, b_in, act_ids, h0);

  StepParams sp;
  sp.h0 = h0;
  sp.extra = extra;
  sp.h1 = h1;
  sp.h2a = h2a;
  sp.h2b = h2b;
  sp.h3 = h3;
  sp.whb = whb;
  sp.b_h = b_h;
  sp.acts = act_ids;
  sp.ss_li = ss_li;
  sp.ss_bp = ss_bp;
  sp.bar = bar;
  void* kp[] = {&sp};
  (void)hipLaunchCooperativeKernel((const void*)step_loop, dim3(NBLOCKS),
                                   dim3(512), kp, 0, stream);

  // all y_t in one GEMM over the stored h4 slots
  ybat_gemm<<<dim3(2, TSTEPS), 256, 0, stream>>>(
      extra, h0, woutb, b_out, out_act, out);
}

// Round 8
// 8845.933 us; speedup vs baseline: 1.6306x; 1.2165x over previous
//
#include <hip/hip_runtime.h>
#include <stdint.h>

// ---------------------------------------------------------------------------
// ComplexApproximateBNN, round 11. R10 post-mortem: phase (20.4us) matches
// per-CU beyond-L1 stream of 384KB (A 128KB bypass + W 256KB L2-thrashed to
// L3) at ~10B/cy/CU. R6's "W in registers" never happened (VGPR=124 < the
// 128 W needs -> compiler rematerialized). R11: true W-stationary.
//  - block = (nt 0..63 x 32 cols, kq 0..3 x K-quarter 1024). W slice =
//    4 layers x 2 ntiles x 4 ksteps x bf16x8 = 128 VGPR, preloaded once,
//    PINNED with asm volatile("":"+v") each step (kills rematerialization).
//  - kq>=1 publish f32 partials as u64 atomic EXCHANGES (proven RMW path),
//    flag++; kq=0 spins flag==3*ph, atomic-loads partials, combines
//    (lo + scale*hi), act, ss, stores h as u64 exchange.
//  - phase-1 h0 operand is pristine (no RMW ever touched it yet) -> plain
//    cached loads. All other A reads: 8B relaxed agent atomic loads.
//  - R10 two-level fence-free barrier unchanged. No fences anywhere.
// ---------------------------------------------------------------------------

typedef __bf16 bf16;
typedef __attribute__((ext_vector_type(8))) __bf16 bf16x8;
typedef __attribute__((ext_vector_type(4))) float f32x4;

#define BATCH 64
#define TSTEPS 128
#define INDIM 512
#define XDIM 2048
#define OUTDIM 256
#define SLOTE ((size_t)BATCH * XDIM)  // elements per [b][2048] slot
#define NBLOCKS 256
#define GSTRIDE 64                    // u32 stride between counters = 256 B

__device__ __forceinline__ float apply_act(float h, int id) {
  switch (id) {
    case 0: return fmaxf(h, 0.0f);                       // relu
    case 1: return 1.0f / (1.0f + __expf(-h));           // sigmoid
    case 2: return tanhf(h);                             // tanh
    case 3: return h >= 0.0f ? h : 0.1f * h;             // leaky 0.1
    default: {                                           // selu
      const float sc = 1.0507009873554805f;
      const float al = 1.6732632423543772f;
      return h > 0.0f ? sc * h : sc * al * (__expf(h) - 1.0f);
    }
  }
}

// Agent-coherent 16B load as 2x8B relaxed atomic loads (proven R5/R9/R10).
__device__ __forceinline__ bf16x8 cload(const bf16* p) {
  union { unsigned long long q[2]; bf16x8 v; } u;
  const unsigned long long* qp = (const unsigned long long*)p;
  u.q[0] = __hip_atomic_load(qp, __ATOMIC_RELAXED, __HIP_MEMORY_SCOPE_AGENT);
  u.q[1] = __hip_atomic_load(qp + 1, __ATOMIC_RELAXED, __HIP_MEMORY_SCOPE_AGENT);
  return u.v;
}

// Coherent 8B store via atomic exchange (RMW at coherence point; proven R9).
__device__ __forceinline__ void cstore8(unsigned long long* p,
                                        unsigned long long v) {
  unsigned long long old = __hip_atomic_exchange(p, v, __ATOMIC_RELAXED,
                                                 __HIP_MEMORY_SCOPE_AGENT);
  asm volatile("" :: "v"(old));
}

__device__ __forceinline__ unsigned long long cload8(
    const unsigned long long* p) {
  return __hip_atomic_load(p, __ATOMIC_RELAXED, __HIP_MEMORY_SCOPE_AGENT);
}

// Two-level fence-free grid barrier (R10-proven). ph is 1-based monotonic.
__device__ __forceinline__ void grid_sync2(unsigned* bars, int bid,
                                           unsigned ph) {
  __syncthreads();
  if (threadIdx.x == 0) {
    const int g = bid >> 5;
    unsigned* garr = bars + (size_t)g * GSTRIDE;
    unsigned* gbar = bars + (size_t)8 * GSTRIDE;
    unsigned* rel  = bars + (size_t)(9 + g) * GSTRIDE;
    unsigned old = __hip_atomic_fetch_add(garr, 1u, __ATOMIC_RELAXED,
                                          __HIP_MEMORY_SCOPE_AGENT);
    if (old == 32u * ph - 1u) {
      unsigned gold = __hip_atomic_fetch_add(gbar, 1u, __ATOMIC_RELAXED,
                                             __HIP_MEMORY_SCOPE_AGENT);
      if (gold != 8u * ph - 1u) {
        while (__hip_atomic_load(gbar, __ATOMIC_RELAXED,
                                 __HIP_MEMORY_SCOPE_AGENT) < 8u * ph) {
          __builtin_amdgcn_s_sleep(4);
        }
      }
      __hip_atomic_fetch_add(rel, 1u, __ATOMIC_RELAXED,
                             __HIP_MEMORY_SCOPE_AGENT);
    } else {
      while (__hip_atomic_load(rel, __ATOMIC_RELAXED,
                               __HIP_MEMORY_SCOPE_AGENT) < ph) {
        __builtin_amdgcn_s_sleep(4);
      }
    }
  }
  __syncthreads();
}

// One layer phase, W-stationary. Block (nt = 32-col tile, kq = K-quarter).
// Computes partial[64,32] = A_kq[64,1024] @ Wslice^T with W in registers.
// kq>=1: publish partial (u64 exchanges) + flag. kq=0: wait 3 flags, read
// partials, combine lo + scale*hi + bias, act, ss, store h.
template <bool SCALE_A2, bool EMIT_SS, bool PLAIN_A1>
__device__ __forceinline__ void layer_phase(
    const int tid, const int nt, const int kq,
    const bf16* __restrict__ A1, const bf16* __restrict__ A2,
    const bf16x8 (&wf)[2][4], const float* __restrict__ bias,
    const int* __restrict__ acts, const float* __restrict__ ss_in,
    float* __restrict__ ss_out, bf16* __restrict__ outb,
    float* __restrict__ pbuf, unsigned* __restrict__ flags,
    const unsigned ph, float (&red)[8][64][33]) {
  const int lane = tid & 63;
  const int w = tid >> 6;        // 0..7 : 128-k slice within the K-quarter
  const int l15 = lane & 15;
  const int kb8 = (lane >> 4) * 8;
  const int q4 = lane >> 4;

  const bf16* As = (kq >= 2) ? A2 : A1;
  const int koff = (kq & 1) * 1024 + w * 128;
  const bf16* ap = As + (size_t)l15 * 2048 + koff + kb8;

  f32x4 acc[4][2];
  const f32x4 zero = {0.f, 0.f, 0.f, 0.f};
#pragma unroll
  for (int mt = 0; mt < 4; mt++) {
    acc[mt][0] = zero;
    acc[mt][1] = zero;
  }

  const bool plain = PLAIN_A1 && (kq < 2);
#pragma unroll
  for (int ks = 0; ks < 4; ks++) {
#pragma unroll
    for (int mt = 0; mt < 4; mt++) {
      const bf16* aptr = ap + (size_t)mt * 16 * 2048 + ks * 32;
      bf16x8 a = plain ? *(const bf16x8*)aptr : cload(aptr);
      acc[mt][0] = __builtin_amdgcn_mfma_f32_16x16x32_bf16(a, wf[0][ks], acc[mt][0], 0, 0, 0);
      acc[mt][1] = __builtin_amdgcn_mfma_f32_16x16x32_bf16(a, wf[1][ks], acc[mt][1], 0, 0, 0);
    }
  }

#pragma unroll
  for (int mt = 0; mt < 4; mt++)
#pragma unroll
    for (int n2 = 0; n2 < 2; n2++)
#pragma unroll
      for (int r = 0; r < 4; r++)
        red[w][mt * 16 + q4 * 4 + r][n2 * 16 + l15] = acc[mt][n2][r];
  __syncthreads();

  // per-thread ownership: row = tid>>3 (0..63), cols c4..c4+3
  const int row = tid >> 3;
  const int c4 = (tid & 7) * 4;
  float v[4];
#pragma unroll
  for (int j = 0; j < 4; j++) {
    float s = 0.f;
#pragma unroll
    for (int ww = 0; ww < 8; ww++) s += red[ww][row][c4 + j];
    v[j] = s;
  }

  const size_t pidx = ((size_t)row) * XDIM + nt * 32 + c4;
  if (kq != 0) {
    // writer: publish partial for this K-quarter
    float* pb = pbuf + (size_t)(kq - 1) * BATCH * XDIM + pidx;
    union { float f[2]; unsigned long long u; } pk;
    pk.f[0] = v[0]; pk.f[1] = v[1];
    cstore8((unsigned long long*)pb, pk.u);
    pk.f[0] = v[2]; pk.f[1] = v[3];
    cstore8((unsigned long long*)(pb + 2), pk.u);
    __syncthreads();  // drain exchanges (vmcnt 0) before flag
    if (tid == 0) {
      __hip_atomic_fetch_add(flags + (size_t)nt * GSTRIDE, 1u,
                             __ATOMIC_RELAXED, __HIP_MEMORY_SCOPE_AGENT);
    }
  } else {
    // combiner
    if (tid == 0) {
      while (__hip_atomic_load(flags + (size_t)nt * GSTRIDE, __ATOMIC_RELAXED,
                               __HIP_MEMORY_SCOPE_AGENT) < 3u * ph) {
        __builtin_amdgcn_s_sleep(2);
      }
    }
    __syncthreads();
    float p1[4], p2[4], p3[4];
#pragma unroll
    for (int h = 0; h < 2; h++) {
      union { unsigned long long u; float f[2]; } u1, u2, u3;
      const unsigned long long* b1 = (const unsigned long long*)(pbuf + pidx) + h;
      u1.u = cload8(b1);
      u2.u = cload8(b1 + (size_t)BATCH * XDIM / 2);
      u3.u = cload8(b1 + (size_t)BATCH * XDIM);
      p1[h * 2] = u1.f[0]; p1[h * 2 + 1] = u1.f[1];
      p2[h * 2] = u2.f[0]; p2[h * 2 + 1] = u2.f[1];
      p3[h * 2] = u3.f[0]; p3[h * 2 + 1] = u3.f[1];
    }
    float scale = 1.0f;
    if (SCALE_A2) {
      float ssv = __hip_atomic_load(ss_in + row, __ATOMIC_RELAXED,
                                    __HIP_MEMORY_SCOPE_AGENT);
      scale = 1.0f / fmaxf(sqrtf(ssv), 1e-12f);
    }
    const int cg = nt * 32 + c4;
    union { bf16 b[4]; unsigned long long u; } hk;
    float ssl = 0.f;
#pragma unroll
    for (int j = 0; j < 4; j++) {
      float lo = v[j] + p1[j];
      float hi = p2[j] + p3[j];
      float pre = (SCALE_A2 ? (lo + scale * hi) : (lo + hi)) + bias[cg + j];
      float av = apply_act(pre, acts[cg + j]);
      hk.b[j] = (bf16)av;
      ssl += av * av;
    }
    if (EMIT_SS) {
      ssl += __shfl_xor(ssl, 1);
      ssl += __shfl_xor(ssl, 2);
      ssl += __shfl_xor(ssl, 4);
      if ((tid & 7) == 0) atomicAdd(ss_out + row, ssl);
    }
    cstore8((unsigned long long*)(outb + (size_t)row * XDIM + cg), hk.u);
  }
}

struct StepParams {
  bf16* h0;           // [128][64][2048], slices also reused as h4 slots 2..
  bf16* extra;        // h4 slots 0,1
  bf16* h1;
  bf16* h2a;
  bf16* h2b;
  bf16* h3;
  const bf16* whb;    // [4][2048][4096]
  const float* b_h;   // [4][2048]
  const int* acts;    // [5][2048]
  float* ss_li;       // [(T+1)*64]
  float* ss_bp;       // [(T+1)*64]
  float* pbuf;        // [3][64][2048] f32 K-quarter partials
  unsigned* flags;    // [64*GSTRIDE] combine flags
  unsigned* bar;      // barrier counters (zeroed), 32*GSTRIDE u32s
};

__global__ __launch_bounds__(512, 2) void step_loop(StepParams p) {
  __shared__ float red[8][64][33];
  const int tid = threadIdx.x;
  const int bid = blockIdx.x;
  const int nt = bid & 63;    // 32-col n-tile
  const int kq = bid >> 6;    // K-quarter (0,1: A1 halves; 2,3: A2 halves)
  const int lane = tid & 63;
  const int w = tid >> 6;
  const int l15 = lane & 15;
  const int kb8 = (lane >> 4) * 8;
  const size_t wstr = (size_t)XDIM * 2 * XDIM;

  // One-time W preload: 4 layers x 2 ntiles x 4 ksteps x bf16x8 = 128 VGPR.
  const bf16* wb = p.whb + (size_t)(nt * 32 + l15) * 4096 + kq * 1024 +
                   w * 128 + kb8;
  bf16x8 wf0[2][4], wf1[2][4], wf2[2][4], wf3[2][4];
#pragma unroll
  for (int n2 = 0; n2 < 2; n2++) {
#pragma unroll
    for (int ks = 0; ks < 4; ks++) {
      const bf16* q = wb + (size_t)n2 * 16 * 4096 + ks * 32;
      wf0[n2][ks] = *(const bf16x8*)q;
      wf1[n2][ks] = *(const bf16x8*)(q + wstr);
      wf2[n2][ks] = *(const bf16x8*)(q + 2 * wstr);
      wf3[n2][ks] = *(const bf16x8*)(q + 3 * wstr);
    }
  }

  unsigned ph = 0;
  for (int t = 0; t < TSTEPS; t++) {
    // Pin W fragments: opaque asm touch defeats rematerialization/reload.
#pragma unroll
    for (int n2 = 0; n2 < 2; n2++)
#pragma unroll
      for (int ks = 0; ks < 4; ks++) {
        asm volatile("" : "+v"(wf0[n2][ks]), "+v"(wf1[n2][ks]),
                          "+v"(wf2[n2][ks]), "+v"(wf3[n2][ks]));
      }

    const bf16* h4t = (t < 2) ? p.extra + (size_t)t * SLOTE
                              : p.h0 + (size_t)(t - 2) * SLOTE;
    bf16* h4n = (t + 1 < 2) ? p.extra + (size_t)(t + 1) * SLOTE
                            : p.h0 + (size_t)(t - 1) * SLOTE;
    bf16* h2n = (t & 1) ? p.h2b : p.h2a;
    const bf16* h2o = (t & 1) ? p.h2a : p.h2b;

    // h1 = act([h0_t, norm(h4_t)] @ W0^T + b0)   (h0 pristine -> plain)
    ++ph;
    layer_phase<true, false, true>(tid, nt, kq, p.h0 + (size_t)t * SLOTE, h4t,
                                   wf0, p.b_h, p.acts + XDIM,
                                   p.ss_bp + t * BATCH, nullptr, p.h1,
                                   p.pbuf, p.flags, ph, red);
    grid_sync2(p.bar, bid, ph);

    // h2 = act([h1, norm(h2_old)] @ W1^T + b1); emit ss_li[t+1]
    ++ph;
    layer_phase<true, true, false>(tid, nt, kq, p.h1, h2o, wf1, p.b_h + XDIM,
                                   p.acts + 2 * XDIM, p.ss_li + t * BATCH,
                                   p.ss_li + (t + 1) * BATCH, h2n,
                                   p.pbuf, p.flags, ph, red);
    grid_sync2(p.bar, bid, ph);

    // h3 = act([h2, h1] @ W2^T + b2)
    ++ph;
    layer_phase<false, false, false>(tid, nt, kq, h2n, p.h1, wf2,
                                     p.b_h + 2 * XDIM, p.acts + 3 * XDIM,
                                     nullptr, nullptr, p.h3,
                                     p.pbuf, p.flags, ph, red);
    grid_sync2(p.bar, bid, ph);

    // h4 = act([h3, h2] @ W3^T + b3) -> slot t+1; emit ss_bp[t+1]
    ++ph;
    layer_phase<false, true, false>(tid, nt, kq, p.h3, h2n, wf3,
                                    p.b_h + 3 * XDIM, p.acts + 4 * XDIM,
                                    nullptr, p.ss_bp + (t + 1) * BATCH, h4n,
                                    p.pbuf, p.flags, ph, red);
    grid_sync2(p.bar, bid, ph);
  }
}

// h0 precompute: [8192,512]@[512->2048], rows r=b*128+t remapped to [t][b][n]
__global__ __launch_bounds__(256) void h0_gemm(
    const bf16* __restrict__ A, const bf16* __restrict__ W,
    const float* __restrict__ bias, const int* __restrict__ acts,
    bf16* __restrict__ outp) {
  const int tid = threadIdx.x;
  const int lane = tid & 63;
  const int wv = tid >> 6;
  const int wm = (wv & 1) * 32;
  const int wn = (wv >> 1) * 64;
  const int nblk = blockIdx.x * 128;
  const int mblk = blockIdx.y * 64;
  const int l15 = lane & 15;
  const int kb8 = (lane >> 4) * 8;

  f32x4 acc[2][4];
  const f32x4 zero = {0.f, 0.f, 0.f, 0.f};
#pragma unroll
  for (int i = 0; i < 2; i++)
#pragma unroll
    for (int j = 0; j < 4; j++) acc[i][j] = zero;

  for (int kt = 0; kt < INDIM; kt += 32) {
    bf16x8 a[2], b[4];
#pragma unroll
    for (int mt = 0; mt < 2; mt++) {
      int m = mblk + wm + mt * 16 + l15;
      a[mt] = *(const bf16x8*)(A + (size_t)m * INDIM + kt + kb8);
    }
#pragma unroll
    for (int nt = 0; nt < 4; nt++) {
      int n = nblk + wn + nt * 16 + l15;
      b[nt] = *(const bf16x8*)(W + (size_t)n * INDIM + kt + kb8);
    }
#pragma unroll
    for (int mt = 0; mt < 2; mt++)
#pragma unroll
      for (int nt = 0; nt < 4; nt++)
        acc[mt][nt] = __builtin_amdgcn_mfma_f32_16x16x32_bf16(a[mt], b[nt], acc[mt][nt], 0, 0, 0);
  }

#pragma unroll
  for (int mt = 0; mt < 2; mt++) {
#pragma unroll
    for (int nt = 0; nt < 4; nt++) {
      int n = nblk + wn + nt * 16 + l15;
      float bv = bias[n];
      int aid = acts[n];
#pragma unroll
      for (int rr = 0; rr < 4; rr++) {
        int m = wm + mt * 16 + (lane >> 4) * 4 + rr;
        float v = apply_act(acc[mt][nt][rr] + bv, aid);
        int rowg = mblk + m;  // = b*128 + t
        int bb = rowg >> 7;
        int tt = rowg & 127;
        outp[((size_t)tt * BATCH + bb) * XDIM + n] = (bf16)v;
      }
    }
  }
}

// batched output layer: for each t, y_t = act(h4slot(t+1) @ Wout^T + bout).
__global__ __launch_bounds__(256) void ybat_gemm(
    const bf16* __restrict__ extra, const bf16* __restrict__ h0,
    const bf16* __restrict__ Wout, const float* __restrict__ bout,
    const int* __restrict__ oact, float* __restrict__ out) {
  const int t = blockIdx.y;
  const int s = t + 1;
  const bf16* A = (s < 2) ? (extra + (size_t)s * SLOTE)
                          : (h0 + (size_t)(s - 2) * SLOTE);
  const int tid = threadIdx.x;
  const int lane = tid & 63;
  const int wv = tid >> 6;
  const int wm = (wv & 1) * 32;
  const int wn = (wv >> 1) * 64;
  const int nblk = blockIdx.x * 128;
  const int l15 = lane & 15;
  const int kb8 = (lane >> 4) * 8;

  f32x4 acc[2][4];
  const f32x4 zero = {0.f, 0.f, 0.f, 0.f};
#pragma unroll
  for (int i = 0; i < 2; i++)
#pragma unroll
    for (int j = 0; j < 4; j++) acc[i][j] = zero;

  for (int kt = 0; kt < XDIM; kt += 32) {
    bf16x8 a[2], b[4];
#pragma unroll
    for (int mt = 0; mt < 2; mt++) {
      int m = wm + mt * 16 + l15;
      a[mt] = *(const bf16x8*)(A + (size_t)m * XDIM + kt + kb8);
    }
#pragma unroll
    for (int nt = 0; nt < 4; nt++) {
      int n = nblk + wn + nt * 16 + l15;
      b[nt] = *(const bf16x8*)(Wout + (size_t)n * XDIM + kt + kb8);
    }
#pragma unroll
    for (int mt = 0; mt < 2; mt++)
#pragma unroll
      for (int nt = 0; nt < 4; nt++)
        acc[mt][nt] = __builtin_amdgcn_mfma_f32_16x16x32_bf16(a[mt], b[nt], acc[mt][nt], 0, 0, 0);
  }

#pragma unroll
  for (int mt = 0; mt < 2; mt++) {
#pragma unroll
    for (int nt = 0; nt < 4; nt++) {
      int n = nblk + wn + nt * 16 + l15;
      float bv = bout[n];
      int aid = oact[n];
#pragma unroll
      for (int rr = 0; rr < 4; rr++) {
        int b = wm + mt * 16 + (lane >> 4) * 4 + rr;  // batch row
        float v = apply_act(acc[mt][nt][rr] + bv, aid);
        out[((size_t)b * TSTEPS + t) * OUTDIM + n] = v;
      }
    }
  }
}

__global__ __launch_bounds__(256) void cvt_bf16(
    const float* __restrict__ in, bf16* __restrict__ out, int n4) {
  int i = blockIdx.x * 256 + threadIdx.x;
  if (i < n4) {
    float4 v = ((const float4*)in)[i];
    union { bf16 b[4]; unsigned long long u; } pk;
    pk.b[0] = (bf16)v.x;
    pk.b[1] = (bf16)v.y;
    pk.b[2] = (bf16)v.z;
    pk.b[3] = (bf16)v.w;
    ((unsigned long long*)out)[i] = pk.u;
  }
}

__global__ __launch_bounds__(256) void zero32(uint32_t* __restrict__ p, int n) {
  int i = blockIdx.x * 256 + threadIdx.x;
  if (i < n) p[i] = 0u;
}

extern "C" void kernel_launch(void* const* d_in, const int* in_sizes, int n_in,
                              void* d_out, int out_size, void* d_ws, size_t ws_size,
                              hipStream_t stream) {
  const float* x     = (const float*)d_in[0];   // [64,128,512]
  const float* W_in  = (const float*)d_in[1];   // [2048,512]
  const float* b_in  = (const float*)d_in[2];   // [2048]
  const float* W_h   = (const float*)d_in[3];   // [4,2048,4096]
  const float* b_h   = (const float*)d_in[4];   // [4,2048]
  const float* W_out = (const float*)d_in[5];   // [256,2048]
  const float* b_out = (const float*)d_in[6];   // [256]
  const int* act_ids = (const int*)d_in[7];     // [5,2048]
  const int* out_act = (const int*)d_in[8];     // [256]
  float* out = (float*)d_out;                   // [64,128,256]

  char* w = (char*)d_ws;
  bf16* xbf   = (bf16*)w; w += (size_t)BATCH * TSTEPS * INDIM * 2;   // 8 MB
  bf16* winb  = (bf16*)w; w += (size_t)XDIM * INDIM * 2;             // 2 MB
  bf16* whb   = (bf16*)w; w += (size_t)4 * XDIM * (2 * XDIM) * 2;    // 64 MB
  bf16* woutb = (bf16*)w; w += (size_t)OUTDIM * XDIM * 2;            // 1 MB
  bf16* h0    = (bf16*)w; w += (size_t)TSTEPS * SLOTE * 2;           // 32 MB (doubles as h4 slots 2..)
  bf16* h1    = (bf16*)w; w += SLOTE * 2;
  bf16* h3    = (bf16*)w; w += SLOTE * 2;
  float* pbuf = (float*)w; w += (size_t)3 * BATCH * XDIM * 4;        // 1.5 MB partials
  // ---- zero region ----
  char* zstart = w;
  bf16* extra = (bf16*)w; w += 2 * SLOTE * 2;   // h4 slots 0,1 (slot 0 must be 0)
  bf16* h2a   = (bf16*)w; w += SLOTE * 2;
  bf16* h2b   = (bf16*)w; w += SLOTE * 2;
  float* ss_li = (float*)w; w += (size_t)(TSTEPS + 1) * BATCH * 4;
  float* ss_bp = (float*)w; w += (size_t)(TSTEPS + 1) * BATCH * 4;
  unsigned* flags = (unsigned*)w; w += (size_t)64 * GSTRIDE * 4;  // combine flags
  unsigned* bar = (unsigned*)w; w += (size_t)32 * GSTRIDE * 4;    // barrier counters
  int zero_u32 = (int)((w - zstart) / 4);

  cvt_bf16<<<4096, 256, 0, stream>>>(x, xbf, (BATCH * TSTEPS * INDIM) / 4);
  cvt_bf16<<<1024, 256, 0, stream>>>(W_in, winb, (XDIM * INDIM) / 4);
  cvt_bf16<<<32768, 256, 0, stream>>>(W_h, whb, (4 * XDIM * 2 * XDIM) / 4);
  cvt_bf16<<<512, 256, 0, stream>>>(W_out, woutb, (OUTDIM * XDIM) / 4);
  zero32<<<(zero_u32 + 255) / 256, 256, 0, stream>>>((uint32_t*)zstart, zero_u32);
  h0_gemm<<<dim3(16, 128), 256, 0, stream>>>(xbf, winb, b_in, act_ids, h0);

  StepParams sp;
  sp.h0 = h0;
  sp.extra = extra;
  sp.h1 = h1;
  sp.h2a = h2a;
  sp.h2b = h2b;
  sp.h3 = h3;
  sp.whb = whb;
  sp.b_h = b_h;
  sp.acts = act_ids;
  sp.ss_li = ss_li;
  sp.ss_bp = ss_bp;
  sp.pbuf = pbuf;
  sp.flags = flags;
  sp.bar = bar;
  void* kp[] = {&sp};
  (void)hipLaunchCooperativeKernel((const void*)step_loop, dim3(NBLOCKS),
                                   dim3(512), kp, 0, stream);

  // all y_t in one GEMM over the stored h4 slots
  ybat_gemm<<<dim3(2, TSTEPS), 256, 0, stream>>>(
      extra, h0, woutb, b_out, out_act, out);
}